// Round 10
// baseline (6696.379 us; speedup 1.0000x reference)
//
#include <hip/hip_runtime.h>

#define NIN  100
#define NOUT 100
#define NHID 500
#define BATCH 256
#define TLEN 300

// ws layout (float offsets)
#define WS_WCT  0       // [100][500]  W_cT[i][j] = (W_ih@W_in)[j][i]
#define WS_BC   50000   // [500]       b_c = W_ih@b_in + b_ih
#define WS_WOT  50500   // [500][100]  W_outT[k][o] = W_out[o][k]
#define WS_WHHT 100500  // [500][512]  W_hhT[k][j] = W_hh[j][k], rows padded to 512
// total 356,500 floats = 1.43 MB (fits ws)

// ---------------- prep: fused weights, transposes ----------------
__global__ __launch_bounds__(256) void prep_kernel(
    const float* __restrict__ W_in, const float* __restrict__ b_in,
    const float* __restrict__ W_ih, const float* __restrict__ b_ih,
    const float* __restrict__ W_out, const float* __restrict__ W_hh,
    float* __restrict__ ws)
{
  int id = blockIdx.x * 256 + threadIdx.x;
  if (id < 50000) {
    int j = id / NIN, i = id % NIN;            // W_c[j][i] = sum_m W_ih[j][m]*W_in[m][i]
    float s = 0.f;
    #pragma unroll 4
    for (int m = 0; m < NHID; m++) s = fmaf(W_ih[j*NHID + m], W_in[m*NIN + i], s);
    ws[WS_WCT + i*NHID + j] = s;               // store transposed: W_cT[i][j]
  } else if (id < 50500) {
    int j = id - 50000;
    float s = b_ih[j];
    #pragma unroll 4
    for (int m = 0; m < NHID; m++) s = fmaf(W_ih[j*NHID + m], b_in[m], s);
    ws[WS_BC + j] = s;
  } else if (id < 100500) {
    int v = id - 50500;                        // v = k*100 + o
    int k = v / NOUT, o = v % NOUT;
    ws[WS_WOT + v] = W_out[o*NHID + k];
  } else if (id < 356500) {
    int v = id - 100500;                       // v = k*512 + j
    int k = v >> 9, j = v & 511;
    ws[WS_WHHT + v] = (j < NHID) ? W_hh[j*NHID + k] : 0.f;
  }
}

// ---------------- pre = input @ W_cT + b_c  ->  written into d_out hidden region ----------------
__global__ __launch_bounds__(256) void pre_gemm_kernel(
    const float* __restrict__ in, const float* __restrict__ ws, float* __restrict__ hid)
{
  __shared__ float A_s[100][68];   // [k][row] transposed input tile
  __shared__ float W_s[100][68];   // [k][j]   W_cT tile
  const int r0 = blockIdx.x * 64;
  const int j0 = blockIdx.y * 64;
  const int tid = threadIdx.x;

  for (int idx = tid; idx < 64*25; idx += 256) {
    int r = idx / 25, kq = idx % 25;
    float4 v = ((const float4*)(in + (size_t)(r0 + r)*NIN))[kq];
    A_s[4*kq+0][r] = v.x; A_s[4*kq+1][r] = v.y; A_s[4*kq+2][r] = v.z; A_s[4*kq+3][r] = v.w;
  }
  for (int idx = tid; idx < 100*16; idx += 256) {
    int k = idx / 16, c4 = idx % 16;
    int j = j0 + c4*4;
    float4 v = make_float4(0.f,0.f,0.f,0.f);
    if (j + 3 < NHID) v = *(const float4*)(ws + WS_WCT + (size_t)k*NHID + j);
    else {
      if (j+0 < NHID) v.x = ws[WS_WCT + k*NHID + j+0];
      if (j+1 < NHID) v.y = ws[WS_WCT + k*NHID + j+1];
      if (j+2 < NHID) v.z = ws[WS_WCT + k*NHID + j+2];
    }
    *(float4*)&W_s[k][c4*4] = v;
  }
  __syncthreads();

  const int jj = tid & 15, rr = tid >> 4;
  float acc[4][4] = {};
  #pragma unroll 4
  for (int k = 0; k < 100; k++) {
    float4 av = *(const float4*)&A_s[k][rr*4];
    float4 wv = *(const float4*)&W_s[k][jj*4];
    float aa[4] = {av.x, av.y, av.z, av.w};
    float ww[4] = {wv.x, wv.y, wv.z, wv.w};
    #pragma unroll
    for (int r = 0; r < 4; r++)
      #pragma unroll
      for (int c = 0; c < 4; c++)
        acc[r][c] = fmaf(aa[r], ww[c], acc[r][c]);
  }
  #pragma unroll
  for (int r = 0; r < 4; r++) {
    int row = r0 + rr*4 + r;
    #pragma unroll
    for (int c = 0; c < 4; c++) {
      int j = j0 + jj*4 + c;
      if (j < NHID) hid[(size_t)row*NHID + j] = acc[r][c] + ws[WS_BC + j];
    }
  }
}

// ---------------- persistent recurrence: SYNC-FREE ----------------
// 64 blocks x 4 batch rows; each block computes ALL 500 columns of its rows every step.
// h[4][500] in LDS (transposed [k][r], uniform ds_read_b128 broadcasts); thread j owns
// column j for all 4 rows (h kept in registers). W_hhT streamed from L2 (1 MB/step/block,
// L2-resident per XCD). Zero inter-block communication, zero global atomics.
__global__ __launch_bounds__(512) void rnn_step_kernel(
    const float* __restrict__ ws, const float* __restrict__ b_hh,
    const float* __restrict__ alpha_w, const float* __restrict__ hidden0,
    float* __restrict__ hid, float* __restrict__ hfinal)
{
  __shared__ float hT[NHID*4];          // [k][r], 8 KB

  const int tid = threadIdx.x;
  const int r0  = blockIdx.x * 4;
  const int j   = tid;                  // column owned by this thread
  const bool jv = (j < NHID);

  // init hT from hidden0  (hT[k*4+r] = h0[r0+r][k])
  for (int idx = tid; idx < NHID*4; idx += 512) {
    int r = idx / NHID, k = idx - r*NHID;
    hT[k*4 + r] = hidden0[(size_t)(r0 + r)*NHID + k];
  }
  // this thread's column state for the 4 rows
  float hreg[4];
  #pragma unroll
  for (int r = 0; r < 4; r++)
    hreg[r] = jv ? hidden0[(size_t)(r0 + r)*NHID + j] : 0.f;

  const float a  = jv ? alpha_w[j] : 0.f;
  const float bh = jv ? b_hh[j]    : 0.f;
  const float* __restrict__ wcol = ws + WS_WHHT + j;   // lane-varying column base

  __syncthreads();

  for (int t = 0; t < TLEN; t++) {
    // prefetch pre-activation values (exclusive (r0+r, t, j) slots; hidden under k-loop)
    size_t offs[4];
    float pre[4];
    #pragma unroll
    for (int r = 0; r < 4; r++) {
      offs[r] = ((size_t)(r0 + r)*TLEN + t)*NHID + j;
      pre[r]  = jv ? hid[offs[r]] : 0.f;
    }

    // dot products: acc[r] = sum_k W_hh[j][k] * h[r][k]
    float acc[4] = {0.f, 0.f, 0.f, 0.f};
    #pragma unroll 8
    for (int k = 0; k < NHID; k++) {
      float  w  = wcol[(size_t)k << 9];            // W_hhT[k][j], coalesced across lanes
      float4 h4 = *(const float4*)&hT[k*4];        // uniform address -> broadcast
      acc[0] = fmaf(w, h4.x, acc[0]);
      acc[1] = fmaf(w, h4.y, acc[1]);
      acc[2] = fmaf(w, h4.z, acc[2]);
      acc[3] = fmaf(w, h4.w, acc[3]);
    }

    __syncthreads();   // everyone done READING hT for step t

    if (jv) {
      #pragma unroll
      for (int r = 0; r < 4; r++) {
        float hc = fmaxf(acc[r] + bh + pre[r], 0.f);
        float hn = (1.f - a)*hreg[r] + a*hc;
        hreg[r] = hn;
        hT[j*4 + r] = hn;            // publish to blockmates
        hid[offs[r]] = hn;           // stream hidden_list
      }
      if (t == TLEN-1) {
        #pragma unroll
        for (int r = 0; r < 4; r++)
          hfinal[(size_t)(r0 + r)*NHID + j] = hreg[r];
      }
    }
    __syncthreads();   // hT updated before next step's reads
  }
}

// ---------------- output projection: out = hidden_list @ W_outT + b_out ----------------
__global__ __launch_bounds__(256) void out_proj_kernel(
    const float* __restrict__ hid, const float* __restrict__ ws,
    const float* __restrict__ b_out, float* __restrict__ outp)
{
  __shared__ float A_s[100][68];
  __shared__ float W_s[100][68];
  const int r0 = blockIdx.x * 64;
  const int o0 = blockIdx.y * 64;
  const int tid = threadIdx.x;
  const int jj = tid & 15, rr = tid >> 4;
  float acc[4][4] = {};

  for (int kc = 0; kc < NHID; kc += 100) {
    __syncthreads();
    for (int idx = tid; idx < 64*25; idx += 256) {
      int r = idx / 25, kq = idx % 25;
      float4 v = ((const float4*)(hid + (size_t)(r0 + r)*NHID + kc))[kq];
      A_s[4*kq+0][r] = v.x; A_s[4*kq+1][r] = v.y; A_s[4*kq+2][r] = v.z; A_s[4*kq+3][r] = v.w;
    }
    for (int idx = tid; idx < 100*16; idx += 256) {
      int k = idx / 16, c4 = idx % 16;
      int o = o0 + c4*4;
      float4 v = make_float4(0.f,0.f,0.f,0.f);
      if (o + 3 < NOUT) v = *(const float4*)(ws + WS_WOT + (size_t)(kc + k)*NOUT + o);
      *(float4*)&W_s[k][c4*4] = v;
    }
    __syncthreads();
    #pragma unroll 2
    for (int k = 0; k < 100; k++) {
      float4 av = *(const float4*)&A_s[k][rr*4];
      float4 wv = *(const float4*)&W_s[k][jj*4];
      float aa[4] = {av.x, av.y, av.z, av.w};
      float ww[4] = {wv.x, wv.y, wv.z, wv.w};
      #pragma unroll
      for (int r = 0; r < 4; r++)
        #pragma unroll
        for (int c = 0; c < 4; c++)
          acc[r][c] = fmaf(aa[r], ww[c], acc[r][c]);
    }
  }
  #pragma unroll
  for (int r = 0; r < 4; r++) {
    int row = r0 + rr*4 + r;
    #pragma unroll
    for (int c = 0; c < 4; c++) {
      int o = o0 + jj*4 + c;
      if (o < NOUT) outp[(size_t)row*NOUT + o] = acc[r][c] + b_out[o];
    }
  }
}

extern "C" void kernel_launch(void* const* d_in, const int* in_sizes, int n_in,
                              void* d_out, int out_size, void* d_ws, size_t ws_size,
                              hipStream_t stream)
{
  const float* input   = (const float*)d_in[0];
  const float* hidden0 = (const float*)d_in[1];
  const float* W_in    = (const float*)d_in[2];
  const float* b_in    = (const float*)d_in[3];
  const float* W_ih    = (const float*)d_in[4];
  const float* b_ih    = (const float*)d_in[5];
  const float* W_hh    = (const float*)d_in[6];
  const float* b_hh    = (const float*)d_in[7];
  const float* W_out   = (const float*)d_in[8];
  const float* b_out   = (const float*)d_in[9];
  const float* alpha_w = (const float*)d_in[10];

  float* ws   = (float*)d_ws;
  float* hid  = (float*)d_out;                        // [256][300][500]
  float* outp = hid  + (size_t)BATCH*TLEN*NHID;       // [256][300][100]
  float* hfin = outp + (size_t)BATCH*TLEN*NOUT;       // [256][500]

  hipLaunchKernelGGL(prep_kernel,     dim3(1393),     dim3(256), 0, stream,
                     W_in, b_in, W_ih, b_ih, W_out, W_hh, ws);
  hipLaunchKernelGGL(pre_gemm_kernel, dim3(1200, 8),  dim3(256), 0, stream,
                     input, ws, hid);
  hipLaunchKernelGGL(rnn_step_kernel, dim3(64),       dim3(512), 0, stream,
                     ws, b_hh, alpha_w, hidden0, hid, hfin);
  hipLaunchKernelGGL(out_proj_kernel, dim3(1200, 2),  dim3(256), 0, stream,
                     hid, ws, b_out, outp);
}